// Round 7
// baseline (746.639 us; speedup 1.0000x reference)
//
#include <hip/hip_runtime.h>

#define TPB 256

// clang ext_vector types for nontemporal builtins (HIP_vector_type is rejected)
typedef float ntf4 __attribute__((ext_vector_type(4)));
typedef int   nti4 __attribute__((ext_vector_type(4)));

// ---- LDS-binned scatter parameters ----
// Split endpoint passes, one histogram per block: 81408 B LDS, 2 blocks/CU.
// Decomposition: 102 stripe-groups; group m = all 10 blocks touching stripe m
// (5 node-ranges x 2 endpoint passes). Blocks of a group share bid%8 -> same
// XCD (dispatch round-robins XCDs by blockIdx) -> the group's w stripe is
// L2-multicast x10 and each idx stripe x5. Compulsory HBM = 307 MB.
// Round-6 lesson: per-wave load rate ∝ independent loads per iteration
// (VGPR=12 proved zero pipelining) -> depth-1 software prefetch via
// loop-carried values, NO sched_barrier (R5 regression).
#define SCAT_TPB 1024
#define S_RANGE  20352
#define SCAT_M   102         // stripes (13 groups per XCD ceil)
#define SCAT_GRID 1040       // 8 XCDs * 13 group-slots * 10 blocks

__device__ __forceinline__ unsigned xcc_id() {
    unsigned v;
    asm volatile("s_getreg_b32 %0, hwreg(HW_REG_XCC_ID)" : "=s"(v));
    return v & 7u;
}

// replicas: R copies of [out_deg (N) | in_deg (N)] back to back in ws.
// R computed identically on device in every kernel: min(8, ws_floats/(2N)).
__device__ __forceinline__ int calc_R(unsigned long long ws_bytes, int N) {
    unsigned long long ws_floats = ws_bytes / 4ull;
    unsigned long long r = ws_floats / (unsigned long long)(2 * N);
    if (r > 8ull) r = 8ull;
    if (r < 1ull) r = 1ull;
    return (int)r;
}

// ---- kernel 1: zero R*2N floats of replica space ----
__global__ void ewn_zero_kernel(float* __restrict__ ws,
                                const int* __restrict__ pN,
                                unsigned long long ws_bytes) {
    int N = *pN;
    int R = calc_R(ws_bytes, N);
    long long total = (long long)R * 2 * N;
    for (long long i = blockIdx.x * (long long)blockDim.x + threadIdx.x; i < total;
         i += (long long)gridDim.x * blockDim.x) {
        ws[i] = 0.0f;
    }
}

// ---- kernel 2: XCD-grouped single-endpoint histogram passes ----
__global__ __launch_bounds__(SCAT_TPB, 8) void ewn_scatter_kernel(
        const float* __restrict__ w,
        const int* __restrict__ src,
        const int* __restrict__ dst,
        float* __restrict__ ws,
        const int* __restrict__ pN,
        unsigned long long ws_bytes,
        int E) {
    __shared__ float h[S_RANGE];

    const int N = *pN;
    const int R = calc_R(ws_bytes, N);
    int NR = (N + S_RANGE - 1) / S_RANGE;   // 5 for N=100K
    if (NR < 1) NR = 1;

    // XCD-aligned decomposition: all 10 blocks of stripe-group m share bid%8.
    const int x   = (int)blockIdx.x & 7;    // target XCD
    const int k   = (int)blockIdx.x >> 3;
    const int sub = k % 10;                 // 5 ranges x 2 passes
    const int gi  = k / 10;
    const int m   = gi * 8 + x;             // stripe index
    if (m >= SCAT_M) return;
    const int pass = sub & 1;               // 0: src/out_deg, 1: dst/in_deg
    const int r0   = sub >> 1;              // node-range 0..4
    const int* __restrict__ idx = pass ? dst : src;

    // stripe bounds, 4-element aligned so float4/int4 loads stay 16B-aligned
    long long stripe = (((long long)E + SCAT_M - 1) / SCAT_M + 3ll) & ~3ll;
    long long jstart = (long long)m * stripe;
    long long jend   = jstart + stripe;
    if (jend > E) jend = E;

    const long long STEP = (long long)SCAT_TPB * 4;
    const unsigned xcc = xcc_id();

    // r-loop runs once for N<=101760; kept for correctness at any N.
    for (int r = r0; r < NR; r += 5) {
        const int lo = r * S_RANGE;

        for (int i = threadIdx.x; i < S_RANGE; i += SCAT_TPB) h[i] = 0.0f;
        __syncthreads();

        long long j0 = jstart + (long long)threadIdx.x * 4;
        if (j0 + 3 < jend) {
            // depth-1 software prefetch: next iteration's loads are issued
            // before this iteration's LDS atomics consume (wv, sv).
            float4 wv = *(const float4*)(w + j0);
            int4   sv = *(const int4*)(idx + j0);
            long long jn = j0 + STEP;
            for (; jn + 3 < jend; jn += STEP) {
                float4 wv2 = *(const float4*)(w + jn);
                int4   sv2 = *(const int4*)(idx + jn);
                int t;
                t = sv.x - lo; if ((unsigned)t < (unsigned)S_RANGE) unsafeAtomicAdd(&h[t], wv.x);
                t = sv.y - lo; if ((unsigned)t < (unsigned)S_RANGE) unsafeAtomicAdd(&h[t], wv.y);
                t = sv.z - lo; if ((unsigned)t < (unsigned)S_RANGE) unsafeAtomicAdd(&h[t], wv.z);
                t = sv.w - lo; if ((unsigned)t < (unsigned)S_RANGE) unsafeAtomicAdd(&h[t], wv.w);
                wv = wv2; sv = sv2;
            }
            {
                int t;
                t = sv.x - lo; if ((unsigned)t < (unsigned)S_RANGE) unsafeAtomicAdd(&h[t], wv.x);
                t = sv.y - lo; if ((unsigned)t < (unsigned)S_RANGE) unsafeAtomicAdd(&h[t], wv.y);
                t = sv.z - lo; if ((unsigned)t < (unsigned)S_RANGE) unsafeAtomicAdd(&h[t], wv.z);
                t = sv.w - lo; if ((unsigned)t < (unsigned)S_RANGE) unsafeAtomicAdd(&h[t], wv.w);
            }
            j0 = jn;
        }
        if (j0 < jend) {    // scalar tail (only if E % 4 != 0)
            for (long long j = j0; j < jend; ++j) {
                float wj = w[j];
                int t = idx[j] - lo;
                if ((unsigned)t < (unsigned)S_RANGE) unsafeAtomicAdd(&h[t], wj);
            }
        }
        __syncthreads();

        // flush LDS histogram with coalesced atomics into per-XCD replica
        int hi = N - lo;
        if (hi > S_RANGE) hi = S_RANGE;
        if (R == 8) {
            float* deg = ws + (unsigned long long)xcc * 2ull * N
                            + (pass ? (unsigned long long)N : 0ull);
            for (int i = threadIdx.x; i < hi; i += SCAT_TPB) {
                __hip_atomic_fetch_add(&deg[lo + i], h[i], __ATOMIC_RELAXED, __HIP_MEMORY_SCOPE_WORKGROUP);
            }
        } else {
            float* deg = ws + (unsigned long long)(xcc % (unsigned)R) * 2ull * N
                            + (pass ? (unsigned long long)N : 0ull);
            for (int i = threadIdx.x; i < hi; i += SCAT_TPB) {
                atomicAdd(&deg[lo + i], h[i]);
            }
        }
        __syncthreads();   // h reused by next r iteration
    }
}

// ---- kernel 3: reduce R replicas + rsqrt, result into replica 0 ----
__global__ void ewn_reduce_norm_kernel(float* __restrict__ ws,
                                       const int* __restrict__ pN,
                                       unsigned long long ws_bytes) {
    int N = *pN;
    int R = calc_R(ws_bytes, N);
    long long n2 = 2ll * N;
    for (long long i = blockIdx.x * (long long)blockDim.x + threadIdx.x; i < n2;
         i += (long long)gridDim.x * blockDim.x) {
        float s = 0.0f;
        for (int r = 0; r < R; ++r) s += ws[(long long)r * n2 + i];
        ws[i] = 1.0f / sqrtf(s);   // precise rsqrt to stay under absmax threshold
    }
}

// ---- kernel 4: out[e] = norm_out[src[e]] * norm_in[dst[e]] * w[e] ----
// (unchanged: 220 us, gather-issue-bound at ~0.9 loads/cy/CU, near ceiling)
__global__ __launch_bounds__(TPB, 8) void ewn_gather_kernel(
        const float* __restrict__ w,
        const int* __restrict__ src,
        const int* __restrict__ dst,
        const float* __restrict__ ws,
        const int* __restrict__ pN,
        float* __restrict__ out,
        int E) {
    const int N = *pN;
    const float* norm_out = ws;
    const float* norm_in  = ws + N;

    const long long tid  = (long long)blockIdx.x * blockDim.x + threadIdx.x;
    const long long half = (long long)gridDim.x * blockDim.x * 4;  // elems per batch sweep
    long long ia = tid * 4;
    long long ib = ia + half;

    if (ib + 3 < E) {
        ntf4 wva = __builtin_nontemporal_load((const ntf4*)(w + ia));
        nti4 sva = __builtin_nontemporal_load((const nti4*)(src + ia));
        nti4 dva = __builtin_nontemporal_load((const nti4*)(dst + ia));
        ntf4 wvb = __builtin_nontemporal_load((const ntf4*)(w + ib));
        nti4 svb = __builtin_nontemporal_load((const nti4*)(src + ib));
        nti4 dvb = __builtin_nontemporal_load((const nti4*)(dst + ib));
        __builtin_amdgcn_sched_barrier(0);  // pin the 6 stream loads up-front
        float sa0 = norm_out[sva.x], sa1 = norm_out[sva.y], sa2 = norm_out[sva.z], sa3 = norm_out[sva.w];
        float da0 = norm_in[dva.x],  da1 = norm_in[dva.y],  da2 = norm_in[dva.z],  da3 = norm_in[dva.w];
        float sb0 = norm_out[svb.x], sb1 = norm_out[svb.y], sb2 = norm_out[svb.z], sb3 = norm_out[svb.w];
        float db0 = norm_in[dvb.x],  db1 = norm_in[dvb.y],  db2 = norm_in[dvb.z],  db3 = norm_in[dvb.w];
        __builtin_amdgcn_sched_barrier(0);  // pin the 16 gathers as a cluster
        ntf4 ova, ovb;
        ova.x = sa0 * da0 * wva.x;
        ova.y = sa1 * da1 * wva.y;
        ova.z = sa2 * da2 * wva.z;
        ova.w = sa3 * da3 * wva.w;
        ovb.x = sb0 * db0 * wvb.x;
        ovb.y = sb1 * db1 * wvb.y;
        ovb.z = sb2 * db2 * wvb.z;
        ovb.w = sb3 * db3 * wvb.w;
        __builtin_nontemporal_store(ova, (ntf4*)(out + ia));
        __builtin_nontemporal_store(ovb, (ntf4*)(out + ib));
    } else {
        for (int b = 0; b < 2; ++b) {
            long long i4 = b ? ib : ia;
            if (i4 + 3 < E) {
                ntf4 wv = __builtin_nontemporal_load((const ntf4*)(w + i4));
                nti4 sv = __builtin_nontemporal_load((const nti4*)(src + i4));
                nti4 dv = __builtin_nontemporal_load((const nti4*)(dst + i4));
                ntf4 ov;
                ov.x = norm_out[sv.x] * norm_in[dv.x] * wv.x;
                ov.y = norm_out[sv.y] * norm_in[dv.y] * wv.y;
                ov.z = norm_out[sv.z] * norm_in[dv.z] * wv.z;
                ov.w = norm_out[sv.w] * norm_in[dv.w] * wv.w;
                __builtin_nontemporal_store(ov, (ntf4*)(out + i4));
            } else if (i4 < E) {
                for (long long j = i4; j < E && j < i4 + 4; ++j) {
                    out[j] = norm_out[src[j]] * norm_in[dst[j]] * w[j];
                }
            }
        }
    }
}

extern "C" void kernel_launch(void* const* d_in, const int* in_sizes, int n_in,
                              void* d_out, int out_size, void* d_ws, size_t ws_size,
                              hipStream_t stream) {
    const float* edge_weight = (const float*)d_in[0];
    const int*   src         = (const int*)d_in[1];
    const int*   dst         = (const int*)d_in[2];
    const int*   pN          = (const int*)d_in[3];  // 1-element device array
    float* out = (float*)d_out;
    const int E = in_sizes[0];
    float* ws = (float*)d_ws;
    unsigned long long wsb = (unsigned long long)ws_size;

    // gather: 8 edges per thread (2 batch-strided groups of 4)
    int nBlocksGather = (int)(((long long)E / 8 + TPB - 1) / TPB);
    if (nBlocksGather < 1) nBlocksGather = 1;

    ewn_zero_kernel<<<1024, TPB, 0, stream>>>(ws, pN, wsb);
    ewn_scatter_kernel<<<SCAT_GRID, SCAT_TPB, 0, stream>>>(edge_weight, src, dst, ws, pN, wsb, E);
    ewn_reduce_norm_kernel<<<1024, TPB, 0, stream>>>(ws, pN, wsb);
    ewn_gather_kernel<<<nBlocksGather, TPB, 0, stream>>>(edge_weight, src, dst, ws, pN, out, E);
}